// Round 23
// baseline (38.207 us; speedup 1.0000x reference)
//
#include <hip/hip_runtime.h>

#define TPB  256     // 4 waves; 4-slab ring pipeline, 4-branch FK per slab
#define RPS  64      // rows per slab, one per lane
#define NSL  4       // slabs per block
#define XDIM 99
#define NJ   26
#define OUTW 78
#define SLABF (RPS * XDIM)   // 6336 floats = 25344 B

// slot tables (slot 0 = hip, slots 1..25 follow ORDER)
constexpr int OFF_IDX[NJ] = {0,1,2,3,4,6,7,8,9,11,12,13,14,15,16,17,18,19,20,22,24,25,26,27,28,30};
constexpr int PAR[NJ]     = {-1,0,1,2,3,0,5,6,7,0,9,10,11,12,10,14,15,16,17,17,10,20,21,22,23,23};

__device__ __forceinline__ float fast_rcp(float a)  { return __builtin_amdgcn_rcpf(a); }
__device__ __forceinline__ float fast_sqrt(float a) { return __builtin_amdgcn_sqrtf(a); }

__device__ __forceinline__ void rodrigues(float ax, float ay, float az, float* R) {
    const float EPS = 1.1920928955078125e-07f;   // np.finfo(np.float32).eps
    float t = fast_sqrt(ax*ax + ay*ay + az*az);
    float inv = fast_rcp(t + EPS);
    float r0 = ax*inv, r1 = ay*inv, r2 = az*inv;
    float s, c;
    __sincosf(t, &s, &c);
    float omc = 1.0f - c;
    float r00 = r0*r0, r11 = r1*r1, r22 = r2*r2;
    float r01 = r0*r1, r02 = r0*r2, r12 = r1*r2;
    R[0] = 1.0f - omc*(r11 + r22);
    R[1] = -s*r2 + omc*r01;
    R[2] =  s*r1 + omc*r02;
    R[3] =  s*r2 + omc*r01;
    R[4] = 1.0f - omc*(r00 + r22);
    R[5] = -s*r0 + omc*r12;
    R[6] = -s*r1 + omc*r02;
    R[7] =  s*r0 + omc*r12;
    R[8] = 1.0f - omc*(r00 + r11);
}

#define STEP(s) do {                                                          \
    const int i_  = OFF_IDX[(s)];                                             \
    const int pa_ = PAR[(s)];                                                 \
    float L[9];                                                               \
    rodrigues(row[3*i_+3], row[3*i_+4], row[3*i_+5], L);                      \
    const float o0 = off[3*i_], o1 = off[3*i_+1], o2 = off[3*i_+2];           \
    _Pragma("unroll")                                                         \
    for (int c = 0; c < 3; ++c)                                               \
        pp[(s)][c] = o0*ang[pa_][c] + o1*ang[pa_][3+c] + o2*ang[pa_][6+c]     \
                   + pp[pa_][c];                                              \
    _Pragma("unroll")                                                         \
    for (int j = 0; j < 3; ++j)                                               \
        _Pragma("unroll")                                                     \
        for (int kk = 0; kk < 3; ++kk)                                        \
            ang[(s)][3*j+kk] = L[3*j+0]*ang[pa_][0+kk]                        \
                             + L[3*j+1]*ang[pa_][3+kk]                        \
                             + L[3*j+2]*ang[pa_][6+kk];                       \
} while (0)

// one slab's DMA, 4-way wave split (R21/R22-proven): wave0 = 6 vm-ops,
// waves 1..3 = 7 vm-ops (6 x 16B + one 4B tail).
__device__ __forceinline__ void dma_slab(const float* gsrc, float* lbuf, int w, int l) {
    #pragma unroll
    for (int j = 0; j < 6; ++j) {
        const int jj = 6 * w + j;
        __builtin_amdgcn_global_load_lds(
            (const __attribute__((address_space(1))) unsigned int*)(gsrc + 256*jj + 4*l),
            (__attribute__((address_space(3))) unsigned int*)(lbuf + 256*jj),
            16, 0, 0);
    }
    if (w >= 1) {
        const int kk = w - 1;
        __builtin_amdgcn_global_load_lds(
            (const __attribute__((address_space(1))) unsigned int*)(gsrc + 6144 + 64*kk + l),
            (__attribute__((address_space(3))) unsigned int*)(lbuf + 6144 + 64*kk),
            4, 0, 0);
    }
}

// compute 4-branch FK + pack + flush on one resident slab (R22-proven body).
__device__ __forceinline__ void process_slab(float* slab, float* ob,
                                             const float* __restrict__ off,
                                             int t, int w, int l) {
    const float* row = &slab[l * XDIM];          // stride 99 -> conflict-free
    float ang[NJ][9];
    float pp[NJ][3];

    {   // hip (trunk root, all waves)
        float R[9];
        rodrigues(row[3], row[4], row[5], R);
        #pragma unroll
        for (int q = 0; q < 9; ++q) ang[0][q] = R[q];
        pp[0][0] = off[0] + row[0];
        pp[0][1] = off[1] + row[1];
        pp[0][2] = off[2] + row[2];
    }
    if (w == 0) {                                // both legs: slots 1..8
        #pragma unroll
        for (int s = 1; s <= 8; ++s) STEP(s);
    } else if (w == 1) {                         // spine+head: slots 9..13
        #pragma unroll
        for (int s = 9; s <= 13; ++s) STEP(s);
    } else if (w == 2) {                         // left arm: 9,10 + 14..19
        STEP(9); STEP(10);
        #pragma unroll
        for (int s = 14; s <= 19; ++s) STEP(s);
    } else {                                     // right arm: 9,10 + 20..25
        STEP(9); STEP(10);
        #pragma unroll
        for (int s = 20; s <= 25; ++s) STEP(s);
    }

    // all waves done reading this slab before pack overwrites it
    asm volatile("s_waitcnt lgkmcnt(0)" ::: "memory");
    __builtin_amdgcn_s_barrier();

    {   // pack pos at stride 78, wave-disjoint column ranges
        float* srow = &slab[l * OUTW];
        if (w == 0) {
            #pragma unroll
            for (int s = 1; s <= 8; ++s) {
                srow[3*s+0] = pp[s][0]; srow[3*s+1] = pp[s][1]; srow[3*s+2] = pp[s][2];
            }
        } else if (w == 1) {
            srow[0] = pp[0][0]; srow[1] = pp[0][1]; srow[2] = pp[0][2];
            #pragma unroll
            for (int s = 9; s <= 13; ++s) {
                srow[3*s+0] = pp[s][0]; srow[3*s+1] = pp[s][1]; srow[3*s+2] = pp[s][2];
            }
        } else if (w == 2) {
            #pragma unroll
            for (int s = 14; s <= 19; ++s) {
                srow[3*s+0] = pp[s][0]; srow[3*s+1] = pp[s][1]; srow[3*s+2] = pp[s][2];
            }
        } else {
            #pragma unroll
            for (int s = 20; s <= 25; ++s) {
                srow[3*s+0] = pp[s][0]; srow[3*s+1] = pp[s][1]; srow[3*s+2] = pp[s][2];
            }
        }
    }
    asm volatile("s_waitcnt lgkmcnt(0)" ::: "memory");
    __builtin_amdgcn_s_barrier();                // packed slab visible to all 256

    {   // flush: pure linear copy, 1248 float4, full lines; 5 vm stores/wave
        float4* ob4 = reinterpret_cast<float4*>(ob);
        const float4* b4 = reinterpret_cast<const float4*>(slab);
        #pragma unroll
        for (int j = 0; j < 4; ++j)              // 4*256 = 1024
            ob4[t + 256*j] = b4[t + 256*j];
        if (t < 224) ob4[1024 + t] = b4[1024 + t];
    }
}

// (256,3): VGPR cap ~170 (R22 measured 68). LDS 50688B -> 3 blocks/CU.
// The lever is CONTINUOUS per-block memory traffic (4-deep ring), not TLP.
__global__ __launch_bounds__(TPB, 3) void skel_fk(const float* __restrict__ x,
                                                  const float* __restrict__ off,
                                                  float* __restrict__ out) {
    __shared__ __align__(16) float buf[2][SLABF];     // 2 x 25344 B ring
    const int t = threadIdx.x;
    const int w = t >> 6;                        // wave id 0..3 (uniform)
    const int l = t & 63;                        // lane = row
    const long long row0 = (long long)blockIdx.x * (NSL * RPS);  // 256 rows/block
    const float* gx = x + row0 * XDIM;
    float* ox = out + row0 * OUTW;

    // prologue: fill the ring (slabs 0 and 1 in flight)
    dma_slab(gx,          buf[0], w, l);
    dma_slab(gx + SLABF,  buf[1], w, l);

    // vmcnt accounting (per wave, in-order retirement; w0 issues 6 DMA ops,
    // w1..3 issue 7; flush = 5 stores). Ops issued AFTER slab k's loads:
    //   k=0: D1 -> 6 (w0) ; k=1: F0+D2 -> 11 (w0) ; k=2: F1+D3 -> 11 ; k=3: F2 -> 5
    #pragma unroll
    for (int k = 0; k < NSL; ++k) {
        if (k == 0)      asm volatile("s_waitcnt vmcnt(6)"  ::: "memory");
        else if (k == 3) asm volatile("s_waitcnt vmcnt(5)"  ::: "memory");
        else             asm volatile("s_waitcnt vmcnt(11)" ::: "memory");
        __builtin_amdgcn_s_barrier();            // slab k resident for all waves

        process_slab(buf[k & 1], ox + (long long)k * RPS * OUTW, off, t, w, l);

        // flush's ds_reads done in every wave -> ring slot reusable
        asm volatile("s_waitcnt lgkmcnt(0)" ::: "memory");
        __builtin_amdgcn_s_barrier();

        if (k < NSL - 2)                         // refill ring: slab k+2
            dma_slab(gx + (long long)(k + 2) * SLABF, buf[k & 1], w, l);
    }
}

extern "C" void kernel_launch(void* const* d_in, const int* in_sizes, int n_in,
                              void* d_out, int out_size, void* d_ws, size_t ws_size,
                              hipStream_t stream) {
    const float* x   = (const float*)d_in[0];
    const float* off = (const float*)d_in[1];
    float* out = (float*)d_out;
    const int B = in_sizes[0] / XDIM;      // 262144
    const int grid = B / (NSL * RPS);      // 1024
    skel_fk<<<grid, TPB, 0, stream>>>(x, off, out);
}

// Round 24
// 35.640 us; speedup vs baseline: 1.0720x; 1.0720x over previous
//
#include <hip/hip_runtime.h>

#define TPB  256     // 4 waves share one 64-row slab via 4-branch FK parallelism
#define RPW  64      // rows per block, one per lane (per wave)
#define XDIM 99
#define NJ   26
#define OUTW 78

// slot tables (slot 0 = hip, slots 1..25 follow ORDER)
constexpr int OFF_IDX[NJ] = {0,1,2,3,4,6,7,8,9,11,12,13,14,15,16,17,18,19,20,22,24,25,26,27,28,30};
constexpr int PAR[NJ]     = {-1,0,1,2,3,0,5,6,7,0,9,10,11,12,10,14,15,16,17,17,10,20,21,22,23,23};

__device__ __forceinline__ float fast_rcp(float a)  { return __builtin_amdgcn_rcpf(a); }
__device__ __forceinline__ float fast_sqrt(float a) { return __builtin_amdgcn_sqrtf(a); }

// Unnormalized Rodrigues: R = I + (s/t)*S_a + ((1-c)/t^2)*S_a^2.
// Identical to reference (S = S_a/(t+EPS)): k1 = s/(t+EPS), k2 = (1-c)/(t+EPS)^2.
// Reuses xx,yy,zz for both the norm and R -> ~10% fewer VALU ops per step.
__device__ __forceinline__ void rodrigues(float ax, float ay, float az, float* R) {
    const float EPS = 1.1920928955078125e-07f;   // np.finfo(np.float32).eps
    float xx = ax*ax, yy = ay*ay, zz = az*az;
    float t = fast_sqrt(xx + yy + zz);
    float inv = fast_rcp(t + EPS);
    float s, c;
    __sincosf(t, &s, &c);
    float k1 = s * inv;
    float k2 = (1.0f - c) * (inv * inv);
    float xy = ax*ay, xz = ax*az, yz = ay*az;
    R[0] = 1.0f - k2*(yy + zz);
    R[1] = -k1*az + k2*xy;
    R[2] =  k1*ay + k2*xz;
    R[3] =  k1*az + k2*xy;
    R[4] = 1.0f - k2*(xx + zz);
    R[5] = -k1*ax + k2*yz;
    R[6] = -k1*ay + k2*xz;
    R[7] =  k1*ax + k2*yz;
    R[8] = 1.0f - k2*(xx + yy);
}

// one FK chain step; s is always a constant unrolled index
#define STEP(s) do {                                                          \
    const int i_  = OFF_IDX[(s)];                                             \
    const int pa_ = PAR[(s)];                                                 \
    float L[9];                                                               \
    rodrigues(row[3*i_+3], row[3*i_+4], row[3*i_+5], L);                      \
    const float o0 = off[3*i_], o1 = off[3*i_+1], o2 = off[3*i_+2];           \
    _Pragma("unroll")                                                         \
    for (int c = 0; c < 3; ++c)                                               \
        pp[(s)][c] = o0*ang[pa_][c] + o1*ang[pa_][3+c] + o2*ang[pa_][6+c]     \
                   + pp[pa_][c];                                              \
    _Pragma("unroll")                                                         \
    for (int j = 0; j < 3; ++j)                                               \
        _Pragma("unroll")                                                     \
        for (int kk = 0; kk < 3; ++kk)                                        \
            ang[(s)][3*j+kk] = L[3*j+0]*ang[pa_][0+kk]                        \
                             + L[3*j+1]*ang[pa_][3+kk]                        \
                             + L[3*j+2]*ang[pa_][6+kk];                       \
} while (0)

// (256,4): VGPR cap 128 (R21 measured 76). LDS 25344B -> 6 blocks/CU x 4 waves
// = 24 waves/CU = 6/SIMD.
__global__ __launch_bounds__(TPB, 4) void skel_fk(const float* __restrict__ x,
                                                  const float* __restrict__ off,
                                                  float* __restrict__ out) {
    __shared__ __align__(16) float buf[RPW * XDIM];   // 25344 B, shared by 4 waves
    const int t = threadIdx.x;
    const int w = t >> 6;                        // wave id 0..3 (uniform)
    const int l = t & 63;                        // lane = row
    const int row0 = blockIdx.x * RPW;
    const float* gsrc = x + (long long)row0 * XDIM;

    // ---- linear DMA (R17-proven pattern), split 4 ways: 6 x 16B per wave,
    //      plus one 4B tail op for waves 1..3 ----
    #pragma unroll
    for (int j = 0; j < 6; ++j) {
        const int jj = 6 * w + j;
        __builtin_amdgcn_global_load_lds(
            (const __attribute__((address_space(1))) unsigned int*)(gsrc + 256*jj + 4*l),
            (__attribute__((address_space(3))) unsigned int*)(buf + 256*jj),
            16, 0, 0);
    }
    if (w >= 1) {
        const int kk = w - 1;
        __builtin_amdgcn_global_load_lds(
            (const __attribute__((address_space(1))) unsigned int*)(gsrc + 6144 + 64*kk + l),
            (__attribute__((address_space(3))) unsigned int*)(buf + 6144 + 64*kk),
            4, 0, 0);
    }
    __syncthreads();                             // all DMA drained & visible

    const float* row = &buf[l * XDIM];           // stride 99 -> conflict-free
    float ang[NJ][9];                            // only this wave's slots touched
    float pp[NJ][3];                             // -> SSA reclaims the rest

    // hip (trunk root, all waves)
    {
        float R[9];
        rodrigues(row[3], row[4], row[5], R);
        #pragma unroll
        for (int q = 0; q < 9; ++q) ang[0][q] = R[q];
        pp[0][0] = off[0] + row[0];
        pp[0][1] = off[1] + row[1];
        pp[0][2] = off[2] + row[2];
    }

    if (w == 0) {                                // both legs: slots 1..8
        #pragma unroll
        for (int s = 1; s <= 8; ++s) STEP(s);
    } else if (w == 1) {                         // spine+head: slots 9..13
        #pragma unroll
        for (int s = 9; s <= 13; ++s) STEP(s);
    } else if (w == 2) {                         // left arm: 9,10 (redundant) + 14..19
        STEP(9); STEP(10);
        #pragma unroll
        for (int s = 14; s <= 19; ++s) STEP(s);
    } else {                                     // right arm: 9,10 (redundant) + 20..25
        STEP(9); STEP(10);
        #pragma unroll
        for (int s = 20; s <= 25; ++s) STEP(s);
    }
    __syncthreads();                             // all slab reads done in all waves

    // ---- pack pos into dead slab at stride 78; wave-disjoint column ranges ----
    {
        float* srow = &buf[l * OUTW];
        if (w == 0) {                            // slots 1..8 -> cols [3,27)
            #pragma unroll
            for (int s = 1; s <= 8; ++s) {
                srow[3*s+0] = pp[s][0]; srow[3*s+1] = pp[s][1]; srow[3*s+2] = pp[s][2];
            }
        } else if (w == 1) {                     // slot 0 + 9..13 -> [0,3)+[27,42)
            srow[0] = pp[0][0]; srow[1] = pp[0][1]; srow[2] = pp[0][2];
            #pragma unroll
            for (int s = 9; s <= 13; ++s) {
                srow[3*s+0] = pp[s][0]; srow[3*s+1] = pp[s][1]; srow[3*s+2] = pp[s][2];
            }
        } else if (w == 2) {                     // slots 14..19 -> [42,60)
            #pragma unroll
            for (int s = 14; s <= 19; ++s) {
                srow[3*s+0] = pp[s][0]; srow[3*s+1] = pp[s][1]; srow[3*s+2] = pp[s][2];
            }
        } else {                                 // slots 20..25 -> [60,78)
            #pragma unroll
            for (int s = 20; s <= 25; ++s) {
                srow[3*s+0] = pp[s][0]; srow[3*s+1] = pp[s][1]; srow[3*s+2] = pp[s][2];
            }
        }
    }
    __syncthreads();                             // packed slab visible to all 256

    // ---- flush: pure linear copy, 1248 float4, full 64B lines, single touch ----
    {
        float4* ob4 = reinterpret_cast<float4*>(out + (long long)row0 * OUTW);
        const float4* b4 = reinterpret_cast<const float4*>(buf);
        #pragma unroll
        for (int j = 0; j < 4; ++j)              // 4*256 = 1024
            ob4[t + 256*j] = b4[t + 256*j];
        if (t < 224) ob4[1024 + t] = b4[1024 + t];
    }
}

extern "C" void kernel_launch(void* const* d_in, const int* in_sizes, int n_in,
                              void* d_out, int out_size, void* d_ws, size_t ws_size,
                              hipStream_t stream) {
    const float* x   = (const float*)d_in[0];
    const float* off = (const float*)d_in[1];
    float* out = (float*)d_out;
    const int B = in_sizes[0] / XDIM;      // 262144
    const int grid = B / RPW;              // 4096
    skel_fk<<<grid, TPB, 0, stream>>>(x, off, out);
}